// Round 2
// baseline (730.007 us; speedup 1.0000x reference)
//
#include <hip/hip_runtime.h>

typedef unsigned short u16;
typedef unsigned long long u64;
typedef __attribute__((ext_vector_type(8))) short bf16x8;
typedef __attribute__((ext_vector_type(4))) float f32x4;
typedef __attribute__((ext_vector_type(4))) unsigned int u32x4;

#define NEGF -3.0e38f

__device__ __forceinline__ u16 f2bf(float x) {
  union { float f; unsigned int u; } v; v.f = x;
  unsigned int r = v.u + 0x7fffu + ((v.u >> 16) & 1u);
  return (u16)(r >> 16);
}
__device__ __forceinline__ float bf2f(u16 b) {
  union { unsigned int u; float f; } v; v.u = ((unsigned int)b) << 16;
  return v.f;
}

// ---- graph [N][N] fp32 -> bitmask [N][64] u64 ----
__global__ __launch_bounds__(256) void pack_kernel(const float* __restrict__ graph,
                                                   u64* __restrict__ bits) {
  const int n = blockIdx.x;
  const int w = threadIdx.x >> 6, lane = threadIdx.x & 63;
  const float* gr = graph + (size_t)n * 4096;
  for (int j = 0; j < 16; ++j) {
    const int wd = j * 4 + w;
    u64 m = __ballot(gr[wd * 64 + lane] != 0.0f);
    if (lane == 0) bits[(size_t)n * 64 + wd] = m;
  }
}

// ---- h1 = x @ Ws[h] (fp32), split-3 to bf16 a+b+c; layout [B*H][4096][64] ----
__global__ __launch_bounds__(256) void h1_kernel(const float* __restrict__ x,
                                                 const float* __restrict__ Ws,
                                                 u16* __restrict__ h1a, u16* __restrict__ h1b,
                                                 u16* __restrict__ h1c) {
  const int blk = blockIdx.x;               // b*4096 + n
  const int h = threadIdx.x >> 6, d = threadIdx.x & 63;
  const float* xr = x + (size_t)blk * 16;
  const float* Wp = Ws + h * (16 * 64) + d;
  float acc = 0.f;
  #pragma unroll
  for (int c = 0; c < 16; ++c) acc += xr[c] * Wp[c * 64];
  const int b = blk >> 12, n = blk & 4095;
  const size_t o = ((size_t)(b * 4 + h) * 4096 + n) * 64 + d;
  u16 a = f2bf(acc);
  float r1 = acc - bf2f(a);        // exact
  u16 bq = f2bf(r1);
  float r2 = r1 - bf2f(bq);        // exact
  h1a[o] = a; h1b[o] = bq; h1c[o] = f2bf(r2);
}

// ---- bf16 [P][4096][64] -> [P][64][4096] ----
__global__ __launch_bounds__(256) void transpose_kernel(const u16* __restrict__ src,
                                                        u16* __restrict__ dst) {
  const int p = blockIdx.y, n0 = blockIdx.x * 64;
  const u16* s = src + (size_t)p * 4096 * 64;
  u16* d = dst + (size_t)p * 4096 * 64;
  __shared__ u16 tile[64][66];
  const int col = threadIdx.x & 63, r4 = threadIdx.x >> 6;
  #pragma unroll
  for (int i = 0; i < 16; ++i) {
    const int r = i * 4 + r4;
    tile[r][col] = s[(size_t)(n0 + r) * 64 + col];
  }
  __syncthreads();
  #pragma unroll
  for (int i = 0; i < 16; ++i) {
    const int r = i * 4 + r4;
    d[(size_t)r * 4096 + n0 + col] = tile[col][r];
  }
}

// ---- h2 = cat @ W_out (fp32), split-3 ----
__global__ __launch_bounds__(256) void h2_kernel(const float* __restrict__ cat,
                                                 const float* __restrict__ Wout,
                                                 u16* __restrict__ h2a, u16* __restrict__ h2b,
                                                 u16* __restrict__ h2c) {
  const int row = blockIdx.x * 4 + (threadIdx.x >> 6);   // 0..16383
  const int d = threadIdx.x & 63;
  const float* cr = cat + (size_t)row * 256;
  float acc = 0.f;
  for (int c4 = 0; c4 < 64; ++c4) {
    const float4 cv = *(const float4*)(cr + c4 * 4);
    acc += cv.x * Wout[(c4 * 4 + 0) * 64 + d];
    acc += cv.y * Wout[(c4 * 4 + 1) * 64 + d];
    acc += cv.z * Wout[(c4 * 4 + 2) * 64 + d];
    acc += cv.w * Wout[(c4 * 4 + 3) * 64 + d];
  }
  const size_t o = (size_t)row * 64 + d;
  u16 a = f2bf(acc);
  float r1 = acc - bf2f(a);
  u16 bq = f2bf(r1);
  float r2 = r1 - bf2f(bq);
  h2a[o] = a; h2b[o] = bq; h2c[o] = f2bf(r2);
}

// ---- flash attention, split-3 logits / split-2 PV ----
// Ha/Hb/Hc: [P][4096][64]; HaT/HbT: [P][64][4096]; bits: [4096][64] u64
// LAYER==1: outp = cat fp32 [4][4096][256] (leaky applied), bias = bs[h][64]
// LAYER==2: outp = d_out fp32 [4][4096][64] (leaky applied), bias = b_out[64]
template <int LAYER>
__global__ __launch_bounds__(256) void attn_kernel(
    const u16* __restrict__ Ha, const u16* __restrict__ Hb, const u16* __restrict__ Hc,
    const u16* __restrict__ HaT, const u16* __restrict__ HbT,
    const u64* __restrict__ bits, const float* __restrict__ bias,
    float* __restrict__ outp) {
  const int pass = blockIdx.y;
  const int t = threadIdx.x;
  const int w = t >> 6;
  const int lane = t & 63, c = lane & 15, g = lane >> 4;
  const int qw = blockIdx.x * 64 + w * 16;        // wave's 16 q-rows
  const size_t poff = (size_t)pass * (4096 * 64);

  __shared__ u16 Ka[64 * 64], Kb[64 * 64], Kc[64 * 64], Va[64 * 64], Vb[64 * 64];
  __shared__ u16 Pa[4][16 * 64], Pb[4][16 * 64];

  // Q fragments: A-operand, lane holds row (qw+c), d = 8g..8g+7 (+32 per kk)
  bf16x8 qa[2], qb[2], qc[2];
  {
    const size_t ro = poff + (size_t)(qw + c) * 64 + 8 * g;
    qa[0] = *(const bf16x8*)(Ha + ro); qa[1] = *(const bf16x8*)(Ha + ro + 32);
    qb[0] = *(const bf16x8*)(Hb + ro); qb[1] = *(const bf16x8*)(Hb + ro + 32);
    qc[0] = *(const bf16x8*)(Hc + ro); qc[1] = *(const bf16x8*)(Hc + ro + 32);
  }

  f32x4 zero4 = {0.f, 0.f, 0.f, 0.f};
  f32x4 Of[4];
  #pragma unroll
  for (int nt = 0; nt < 4; ++nt) Of[nt] = zero4;
  float mrow[4] = {NEGF, NEGF, NEGF, NEGF};
  float lrow[4] = {0.f, 0.f, 0.f, 0.f};

  const u64* bq = bits + (size_t)(qw + 4 * g) * 64;

  for (int ch = 0; ch < 64; ++ch) {
    const int k0 = ch * 64;
    __syncthreads();
    // stage K (3 comps) / V (2 comps) 64x64 bf16 tiles, XOR-swizzled rows
    #pragma unroll
    for (int it = 0; it < 2; ++it) {
      const int idx = t + it * 256;
      const int row = idx >> 3, cb = (idx & 7) << 4;
      const int sw = row * 128 + (cb ^ ((row & 7) << 4));
      const size_t go = poff + (size_t)(k0 + row) * 64;
      const size_t gt = poff + (size_t)row * 4096 + k0;
      *(u32x4*)((char*)Ka + sw) = *(const u32x4*)((const char*)(Ha + go) + cb);
      *(u32x4*)((char*)Kb + sw) = *(const u32x4*)((const char*)(Hb + go) + cb);
      *(u32x4*)((char*)Kc + sw) = *(const u32x4*)((const char*)(Hc + go) + cb);
      *(u32x4*)((char*)Va + sw) = *(const u32x4*)((const char*)(HaT + gt) + cb);
      *(u32x4*)((char*)Vb + sw) = *(const u32x4*)((const char*)(HbT + gt) + cb);
    }
    __syncthreads();

    // S = Q K^T  (split-3, 6 terms, small->large), D: row=4g+i (q), col=c
    f32x4 s[4];
    #pragma unroll
    for (int mt = 0; mt < 4; ++mt) {
      const int row = mt * 16 + c;
      const int rb = row * 128, swz = (row & 7) << 4;
      f32x4 acc = zero4;
      #pragma unroll
      for (int kk = 0; kk < 2; ++kk) {
        const int cb = (g * 16 + kk * 64) ^ swz;
        const bf16x8 kaf = *(const bf16x8*)((const char*)Ka + rb + cb);
        const bf16x8 kbf = *(const bf16x8*)((const char*)Kb + rb + cb);
        const bf16x8 kcf = *(const bf16x8*)((const char*)Kc + rb + cb);
        acc = __builtin_amdgcn_mfma_f32_16x16x32_bf16(qc[kk], kaf, acc, 0, 0, 0);
        acc = __builtin_amdgcn_mfma_f32_16x16x32_bf16(qb[kk], kbf, acc, 0, 0, 0);
        acc = __builtin_amdgcn_mfma_f32_16x16x32_bf16(qa[kk], kcf, acc, 0, 0, 0);
        acc = __builtin_amdgcn_mfma_f32_16x16x32_bf16(qb[kk], kaf, acc, 0, 0, 0);
        acc = __builtin_amdgcn_mfma_f32_16x16x32_bf16(qa[kk], kbf, acc, 0, 0, 0);
        acc = __builtin_amdgcn_mfma_f32_16x16x32_bf16(qa[kk], kaf, acc, 0, 0, 0);
      }
      s[mt] = acc;
    }

    // masked online softmax (fp32), write split-2 P to LDS
    float scl[4];
    #pragma unroll
    for (int i = 0; i < 4; ++i) {
      const u64 mwv = bq[(size_t)i * 64 + ch];
      float sv[4];
      float mm = NEGF;
      #pragma unroll
      for (int mt = 0; mt < 4; ++mt) {
        const bool on = (mwv >> (mt * 16 + c)) & 1ull;
        sv[mt] = on ? s[mt][i] : NEGF;
        mm = fmaxf(mm, sv[mt]);
      }
      #pragma unroll
      for (int dd = 1; dd < 16; dd <<= 1) mm = fmaxf(mm, __shfl_xor(mm, dd));
      const float mn = fmaxf(mrow[i], mm);
      scl[i] = __expf(mrow[i] - mn);
      mrow[i] = mn;
      float rs = 0.f;
      const int prow = 4 * g + i;
      const int prb = prow * 128, pswz = (prow & 7) << 4;
      #pragma unroll
      for (int mt = 0; mt < 4; ++mt) {
        const float pv = (sv[mt] > NEGF) ? __expf(sv[mt] - mn) : 0.f;
        rs += pv;
        const int cb = ((mt * 16 + c) * 2) ^ pswz;
        const u16 pa = f2bf(pv);
        *(u16*)((char*)&Pa[w][0] + prb + cb) = pa;
        *(u16*)((char*)&Pb[w][0] + prb + cb) = f2bf(pv - bf2f(pa));
      }
      #pragma unroll
      for (int dd = 1; dd < 16; dd <<= 1) rs += __shfl_xor(rs, dd);
      lrow[i] = lrow[i] * scl[i] + rs;
    }

    #pragma unroll
    for (int nt = 0; nt < 4; ++nt) {
      Of[nt][0] *= scl[0]; Of[nt][1] *= scl[1];
      Of[nt][2] *= scl[2]; Of[nt][3] *= scl[3];
    }

    // O += P V  (split-2 x split-2, 4 terms, small->large)
    #pragma unroll
    for (int kk = 0; kk < 2; ++kk) {
      const int cbp = (16 * g + 64 * kk) ^ ((c & 7) << 4);
      const bf16x8 paf = *(const bf16x8*)((const char*)&Pa[w][0] + c * 128 + cbp);
      const bf16x8 pbf = *(const bf16x8*)((const char*)&Pb[w][0] + c * 128 + cbp);
      #pragma unroll
      for (int nt = 0; nt < 4; ++nt) {
        const int vrow = nt * 16 + c;
        const int vb_off = vrow * 128 + ((16 * g + 64 * kk) ^ ((vrow & 7) << 4));
        const bf16x8 vaf = *(const bf16x8*)((const char*)Va + vb_off);
        const bf16x8 vbf = *(const bf16x8*)((const char*)Vb + vb_off);
        Of[nt] = __builtin_amdgcn_mfma_f32_16x16x32_bf16(pbf, vbf, Of[nt], 0, 0, 0);
        Of[nt] = __builtin_amdgcn_mfma_f32_16x16x32_bf16(pbf, vaf, Of[nt], 0, 0, 0);
        Of[nt] = __builtin_amdgcn_mfma_f32_16x16x32_bf16(paf, vbf, Of[nt], 0, 0, 0);
        Of[nt] = __builtin_amdgcn_mfma_f32_16x16x32_bf16(paf, vaf, Of[nt], 0, 0, 0);
      }
    }
  }

  // epilogue: normalize, +bias, leaky, store
  #pragma unroll
  for (int i = 0; i < 4; ++i) {
    const float inv = 1.0f / lrow[i];
    const int q = qw + 4 * g + i;
    #pragma unroll
    for (int nt = 0; nt < 4; ++nt) {
      const int d = nt * 16 + c;
      float o;
      if (LAYER == 1) o = Of[nt][i] * inv + bias[(pass & 3) * 64 + d];
      else            o = Of[nt][i] * inv + bias[d];
      o = (o >= 0.f) ? o : 0.2f * o;
      if (LAYER == 1) {
        const int b = pass >> 2;
        outp[((size_t)b * 4096 + q) * 256 + (pass & 3) * 64 + d] = o;
      } else {
        outp[((size_t)pass * 4096 + q) * 64 + d] = o;
      }
    }
  }
}

extern "C" void kernel_launch(void* const* d_in, const int* in_sizes, int n_in,
                              void* d_out, int out_size, void* d_ws, size_t ws_size,
                              hipStream_t stream) {
  const float* x     = (const float*)d_in[0];
  const float* graph = (const float*)d_in[1];
  const float* Ws    = (const float*)d_in[2];
  const float* bs    = (const float*)d_in[3];
  const float* W_out = (const float*)d_in[4];
  const float* b_out = (const float*)d_in[5];
  char* ws = (char*)d_ws;
  const size_t MiB = 1048576;

  u64* bits   = (u64*)(ws + 0 * MiB);      // 2 MiB
  u16* h1a    = (u16*)(ws + 2 * MiB);      // 8 MiB  [16][4096][64]
  u16* h1b    = (u16*)(ws + 10 * MiB);     // 8 MiB
  u16* h1c    = (u16*)(ws + 18 * MiB);     // 8 MiB
  u16* h1aT   = (u16*)(ws + 26 * MiB);     // 8 MiB  [16][64][4096]
  u16* h1bT   = (u16*)(ws + 34 * MiB);     // 8 MiB
  float* catb = (float*)(ws + 42 * MiB);   // 16 MiB [4][4096][256]
  u16* h2a    = (u16*)(ws + 58 * MiB);     // 2 MiB  [4][4096][64]
  u16* h2b    = (u16*)(ws + 60 * MiB);     // 2 MiB
  u16* h2c    = (u16*)(ws + 62 * MiB);     // 2 MiB
  u16* h2aT   = (u16*)(ws + 64 * MiB);     // 2 MiB
  u16* h2bT   = (u16*)(ws + 66 * MiB);     // 2 MiB  (total 68 MiB)

  pack_kernel<<<4096, 256, 0, stream>>>(graph, bits);
  h1_kernel<<<16384, 256, 0, stream>>>(x, Ws, h1a, h1b, h1c);
  transpose_kernel<<<dim3(64, 16), 256, 0, stream>>>(h1a, h1aT);
  transpose_kernel<<<dim3(64, 16), 256, 0, stream>>>(h1b, h1bT);
  attn_kernel<1><<<dim3(64, 16), 256, 0, stream>>>(h1a, h1b, h1c, h1aT, h1bT, bits, bs, catb);
  h2_kernel<<<4096, 256, 0, stream>>>(catb, W_out, h2a, h2b, h2c);
  transpose_kernel<<<dim3(64, 4), 256, 0, stream>>>(h2a, h2aT);
  transpose_kernel<<<dim3(64, 4), 256, 0, stream>>>(h2b, h2bT);
  attn_kernel<2><<<dim3(64, 4), 256, 0, stream>>>(h2a, h2b, h2c, h2aT, h2bT, bits, b_out, (float*)d_out);
}

// Round 3
// 550.274 us; speedup vs baseline: 1.3266x; 1.3266x over previous
//
#include <hip/hip_runtime.h>

typedef unsigned short u16;
typedef unsigned int u32;
typedef unsigned long long u64;
typedef __attribute__((ext_vector_type(8))) short bf16x8;
typedef __attribute__((ext_vector_type(4))) float f32x4;

#define NEGF -3.0e38f

__device__ __forceinline__ u16 f2bf(float x) {
  union { float f; u32 u; } v; v.f = x;
  u32 r = v.u + 0x7fffu + ((v.u >> 16) & 1u);
  return (u16)(r >> 16);
}
__device__ __forceinline__ float bf2f(u16 b) {
  union { u32 u; float f; } v; v.u = ((u32)b) << 16;
  return v.f;
}
__device__ __forceinline__ u32 fbits(float x) {
  union { float f; u32 u; } v; v.f = x; return v.u;
}
__device__ __forceinline__ float bcast(u32 u) {
  union { u32 u; float f; } v; v.u = u; return v.f;
}

// async global->LDS, 16B per lane; LDS dest = wave-uniform base + lane*16
__device__ __forceinline__ void gload16(const void* g, void* l) {
  __builtin_amdgcn_global_load_lds(
      (const __attribute__((address_space(1))) u32*)(unsigned long long)g,
      (__attribute__((address_space(3))) u32*)(u32)(unsigned long long)l,
      16, 0, 0);
}

// ---- graph [N][N] fp32 -> bitmask [N][64] u64 ----
__global__ __launch_bounds__(256) void pack_kernel(const float* __restrict__ graph,
                                                   u64* __restrict__ bits) {
  const int n = blockIdx.x;
  const int w = threadIdx.x >> 6, lane = threadIdx.x & 63;
  const float* gr = graph + (size_t)n * 4096;
  for (int j = 0; j < 16; ++j) {
    const int wd = j * 4 + w;
    u64 m = __ballot(gr[wd * 64 + lane] != 0.0f);
    if (lane == 0) bits[(size_t)n * 64 + wd] = m;
  }
}

// ---- h1 = x @ Ws[h] (fp32), split-3 to bf16 a+b+c; layout [B*H][4096][64] ----
__global__ __launch_bounds__(256) void h1_kernel(const float* __restrict__ x,
                                                 const float* __restrict__ Ws,
                                                 u16* __restrict__ h1a, u16* __restrict__ h1b,
                                                 u16* __restrict__ h1c) {
  const int blk = blockIdx.x;
  const int h = threadIdx.x >> 6, d = threadIdx.x & 63;
  const float* xr = x + (size_t)blk * 16;
  const float* Wp = Ws + h * (16 * 64) + d;
  float acc = 0.f;
  #pragma unroll
  for (int c = 0; c < 16; ++c) acc += xr[c] * Wp[c * 64];
  const int b = blk >> 12, n = blk & 4095;
  const size_t o = ((size_t)(b * 4 + h) * 4096 + n) * 64 + d;
  u16 a = f2bf(acc);
  float r1 = acc - bf2f(a);
  u16 bq = f2bf(r1);
  float r2 = r1 - bf2f(bq);
  h1a[o] = a; h1b[o] = bq; h1c[o] = f2bf(r2);
}

// ---- bf16 [P][4096][64] -> [P][64][4096] ----
__global__ __launch_bounds__(256) void transpose_kernel(const u16* __restrict__ src,
                                                        u16* __restrict__ dst) {
  const int p = blockIdx.y, n0 = blockIdx.x * 64;
  const u16* s = src + (size_t)p * 4096 * 64;
  u16* d = dst + (size_t)p * 4096 * 64;
  __shared__ u16 tile[64][66];
  const int col = threadIdx.x & 63, r4 = threadIdx.x >> 6;
  #pragma unroll
  for (int i = 0; i < 16; ++i) {
    const int r = i * 4 + r4;
    tile[r][col] = s[(size_t)(n0 + r) * 64 + col];
  }
  __syncthreads();
  #pragma unroll
  for (int i = 0; i < 16; ++i) {
    const int r = i * 4 + r4;
    d[(size_t)r * 4096 + n0 + col] = tile[col][r];
  }
}

// ---- h2 = cat @ W_out (fp32), split-3 ----
__global__ __launch_bounds__(256) void h2_kernel(const float* __restrict__ cat,
                                                 const float* __restrict__ Wout,
                                                 u16* __restrict__ h2a, u16* __restrict__ h2b,
                                                 u16* __restrict__ h2c) {
  const int row = blockIdx.x * 4 + (threadIdx.x >> 6);
  const int d = threadIdx.x & 63;
  const float* cr = cat + (size_t)row * 256;
  float acc = 0.f;
  for (int c4 = 0; c4 < 64; ++c4) {
    const float4 cv = *(const float4*)(cr + c4 * 4);
    acc += cv.x * Wout[(c4 * 4 + 0) * 64 + d];
    acc += cv.y * Wout[(c4 * 4 + 1) * 64 + d];
    acc += cv.z * Wout[(c4 * 4 + 2) * 64 + d];
    acc += cv.w * Wout[(c4 * 4 + 3) * 64 + d];
  }
  const size_t o = (size_t)row * 64 + d;
  u16 a = f2bf(acc);
  float r1 = acc - bf2f(a);
  u16 bq = f2bf(r1);
  float r2 = r1 - bf2f(bq);
  h2a[o] = a; h2b[o] = bq; h2c[o] = f2bf(r2);
}

// ---- flash attention: swapped QK^T (S^T layout), split-3 logits / split-2 PV ----
template <int LAYER, int NSUB>
__global__ __launch_bounds__(256, 2) void attn_kernel(
    const u16* __restrict__ Ha, const u16* __restrict__ Hb, const u16* __restrict__ Hc,
    const u16* __restrict__ HaT, const u16* __restrict__ HbT,
    const u64* __restrict__ bits, const float* __restrict__ bias,
    float* __restrict__ outp) {
  constexpr int GX = (NSUB == 2) ? 32 : 64;
  constexpr int GY = (LAYER == 1) ? 16 : 4;
  constexpr int NWG = GX * GY;
  // bijective XCD swizzle: each XCD gets a contiguous chunk (pass-locality in its L2)
  const int orig = blockIdx.x + GX * blockIdx.y;
  const int sid = (orig & 7) * (NWG / 8) + (orig >> 3);
  const int bx = sid % GX;
  const int pass = sid / GX;

  const int t = threadIdx.x;
  const int w = t >> 6;
  const int lane = t & 63, c = lane & 15, g = lane >> 4;
  const int qw = bx * (64 * NSUB) + w * (16 * NSUB);
  const size_t poff = (size_t)pass * (4096 * 64);

  __shared__ u16 Ka[64 * 64], Kb[64 * 64], Kc[64 * 64], Va[64 * 64], Vb[64 * 64];
  __shared__ u16 Pa[4][NSUB][16 * 64], Pb[4][NSUB][16 * 64];

  // precomputed LDS byte indices (all tiles share swz since rows == c mod 8)
  const int swz = (c & 7) << 4;
  const int iK0 = c * 128 + ((16 * g) ^ swz);        // frag read, kk=0
  const int iK1 = c * 128 + ((16 * g + 64) ^ swz);   // frag read, kk=1
  int ipw[4];
  #pragma unroll
  for (int mt = 0; mt < 4; ++mt) ipw[mt] = c * 128 + ((32 * mt + 8 * g) ^ swz);

  // Q fragments (both subtiles, 3 components)
  bf16x8 qa[NSUB][2], qb[NSUB][2], qc[NSUB][2];
  #pragma unroll
  for (int sub = 0; sub < NSUB; ++sub) {
    const size_t ro = poff + (size_t)(qw + sub * 16 + c) * 64 + 8 * g;
    qa[sub][0] = *(const bf16x8*)(Ha + ro); qa[sub][1] = *(const bf16x8*)(Ha + ro + 32);
    qb[sub][0] = *(const bf16x8*)(Hb + ro); qb[sub][1] = *(const bf16x8*)(Hb + ro + 32);
    qc[sub][0] = *(const bf16x8*)(Hc + ro); qc[sub][1] = *(const bf16x8*)(Hc + ro + 32);
  }

  // staging pointers (pre-swizzled global source, linear LDS dest)
  const int lr8 = lane >> 3;
  const int scol = ((lane & 7) ^ lr8) << 4;
  const char* gKa = (const char*)(Ha + poff) + (size_t)(w * 16 + lr8) * 128 + scol;
  const char* gKb = (const char*)(Hb + poff) + (size_t)(w * 16 + lr8) * 128 + scol;
  const char* gKc = (const char*)(Hc + poff) + (size_t)(w * 16 + lr8) * 128 + scol;
  const char* gVa = (const char*)(HaT + poff) + (size_t)(w * 16 + lr8) * 8192 + scol;
  const char* gVb = (const char*)(HbT + poff) + (size_t)(w * 16 + lr8) * 8192 + scol;
  u16* dKa = Ka + w * 16 * 64; u16* dKb = Kb + w * 16 * 64; u16* dKc = Kc + w * 16 * 64;
  u16* dVa = Va + w * 16 * 64; u16* dVb = Vb + w * 16 * 64;

  const u64* bqp[NSUB];
  #pragma unroll
  for (int sub = 0; sub < NSUB; ++sub)
    bqp[sub] = bits + (size_t)(qw + sub * 16 + c) * 64;

  f32x4 zero4 = {0.f, 0.f, 0.f, 0.f};
  f32x4 Of[NSUB][4];
  float mrow[NSUB], lrow[NSUB];
  #pragma unroll
  for (int sub = 0; sub < NSUB; ++sub) {
    mrow[sub] = NEGF; lrow[sub] = 0.f;
    #pragma unroll
    for (int nt = 0; nt < 4; ++nt) Of[sub][nt] = zero4;
  }

  for (int ch = 0; ch < 64; ++ch) {
    __syncthreads();
    #pragma unroll
    for (int hh = 0; hh < 2; ++hh) {
      gload16(gKa + hh * 1024, dKa + hh * 512);
      gload16(gKb + hh * 1024, dKb + hh * 512);
      gload16(gKc + hh * 1024, dKc + hh * 512);
      gload16(gVa + (size_t)hh * 65536, dVa + hh * 512);
      gload16(gVb + (size_t)hh * 65536, dVb + hh * 512);
    }
    gKa += 8192; gKb += 8192; gKc += 8192; gVa += 128; gVb += 128;
    __syncthreads();

    // S^T = K^T Q (6-term split-3, small->large); lane: q=c, k=mt*16+4g+i
    f32x4 sac[NSUB][4];
    #pragma unroll
    for (int sub = 0; sub < NSUB; ++sub)
      #pragma unroll
      for (int mt = 0; mt < 4; ++mt) sac[sub][mt] = zero4;

    __builtin_amdgcn_s_setprio(1);
    #pragma unroll
    for (int mt = 0; mt < 4; ++mt) {
      #pragma unroll
      for (int kk = 0; kk < 2; ++kk) {
        const int ib = (kk ? iK1 : iK0) + mt * 2048;
        const bf16x8 kaf = *(const bf16x8*)((const char*)Ka + ib);
        const bf16x8 kbf = *(const bf16x8*)((const char*)Kb + ib);
        const bf16x8 kcf = *(const bf16x8*)((const char*)Kc + ib);
        #pragma unroll
        for (int sub = 0; sub < NSUB; ++sub) {
          f32x4 a = sac[sub][mt];
          a = __builtin_amdgcn_mfma_f32_16x16x32_bf16(kaf, qc[sub][kk], a, 0, 0, 0);
          a = __builtin_amdgcn_mfma_f32_16x16x32_bf16(kbf, qb[sub][kk], a, 0, 0, 0);
          a = __builtin_amdgcn_mfma_f32_16x16x32_bf16(kcf, qa[sub][kk], a, 0, 0, 0);
          a = __builtin_amdgcn_mfma_f32_16x16x32_bf16(kaf, qb[sub][kk], a, 0, 0, 0);
          a = __builtin_amdgcn_mfma_f32_16x16x32_bf16(kbf, qa[sub][kk], a, 0, 0, 0);
          a = __builtin_amdgcn_mfma_f32_16x16x32_bf16(kaf, qa[sub][kk], a, 0, 0, 0);
          sac[sub][mt] = a;
        }
      }
    }
    __builtin_amdgcn_s_setprio(0);

    // masked online softmax: lane-local row (q=c), reduce over g via 2 shfl_xor
    float scl_s[NSUB];
    #pragma unroll
    for (int sub = 0; sub < NSUB; ++sub) {
      const u64 mwv = bqp[sub][ch];
      const u32 h0 = ((u32)mwv) >> (4 * g);
      const u32 h1 = ((u32)(mwv >> 32)) >> (4 * g);
      float sv[16];
      #pragma unroll
      for (int mt = 0; mt < 4; ++mt) {
        const u32 hs = (mt < 2) ? h0 : h1;
        const int sh = (mt & 1) * 16;
        #pragma unroll
        for (int i = 0; i < 4; ++i)
          sv[mt * 4 + i] = ((hs >> (sh + i)) & 1u) ? sac[sub][mt][i] : NEGF;
      }
      float mx[8];
      #pragma unroll
      for (int j = 0; j < 8; ++j) mx[j] = fmaxf(sv[2 * j], sv[2 * j + 1]);
      #pragma unroll
      for (int j = 0; j < 4; ++j) mx[j] = fmaxf(mx[2 * j], mx[2 * j + 1]);
      float mm = fmaxf(fmaxf(mx[0], mx[1]), fmaxf(mx[2], mx[3]));
      mm = fmaxf(mm, __shfl_xor(mm, 16));
      mm = fmaxf(mm, __shfl_xor(mm, 32));
      const float mn = fmaxf(mrow[sub], mm);
      scl_s[sub] = __expf(mrow[sub] - mn);
      mrow[sub] = mn;
      // exp + re-mask (guards mn==NEGF all-masked case)
      #pragma unroll
      for (int mt = 0; mt < 4; ++mt) {
        const u32 hs = (mt < 2) ? h0 : h1;
        const int sh = (mt & 1) * 16;
        #pragma unroll
        for (int i = 0; i < 4; ++i) {
          const int j = mt * 4 + i;
          const float e = __expf(sv[j] - mn);
          sv[j] = ((hs >> (sh + i)) & 1u) ? e : 0.f;
        }
      }
      float sx[8];
      #pragma unroll
      for (int j = 0; j < 8; ++j) sx[j] = sv[2 * j] + sv[2 * j + 1];
      #pragma unroll
      for (int j = 0; j < 4; ++j) sx[j] = sx[2 * j] + sx[2 * j + 1];
      float rs = (sx[0] + sx[1]) + (sx[2] + sx[3]);
      rs += __shfl_xor(rs, 16);
      rs += __shfl_xor(rs, 32);
      lrow[sub] = lrow[sub] * scl_s[sub] + rs;
      // write split-2 P (trunc hi + trunc lo), packed ds_write_b64
      #pragma unroll
      for (int mt = 0; mt < 4; ++mt) {
        const u32 b0 = fbits(sv[4 * mt + 0]), b1 = fbits(sv[4 * mt + 1]);
        const u32 b2 = fbits(sv[4 * mt + 2]), b3 = fbits(sv[4 * mt + 3]);
        uint2 hv;
        hv.x = (b0 >> 16) | (b1 & 0xffff0000u);
        hv.y = (b2 >> 16) | (b3 & 0xffff0000u);
        const float r0 = sv[4 * mt + 0] - bcast(b0 & 0xffff0000u);
        const float r1 = sv[4 * mt + 1] - bcast(b1 & 0xffff0000u);
        const float r2 = sv[4 * mt + 2] - bcast(b2 & 0xffff0000u);
        const float r3 = sv[4 * mt + 3] - bcast(b3 & 0xffff0000u);
        uint2 lv;
        lv.x = (fbits(r0) >> 16) | (fbits(r1) & 0xffff0000u);
        lv.y = (fbits(r2) >> 16) | (fbits(r3) & 0xffff0000u);
        *(uint2*)((char*)&Pa[w][sub][0] + ipw[mt]) = hv;
        *(uint2*)((char*)&Pb[w][sub][0] + ipw[mt]) = lv;
      }
    }

    // rescale O (broadcast scl from lane c=q to D-row domain)
    #pragma unroll
    for (int sub = 0; sub < NSUB; ++sub) {
      float sf[4];
      #pragma unroll
      for (int i = 0; i < 4; ++i) sf[i] = __shfl(scl_s[sub], 4 * g + i);
      #pragma unroll
      for (int nt = 0; nt < 4; ++nt) {
        Of[sub][nt][0] *= sf[0]; Of[sub][nt][1] *= sf[1];
        Of[sub][nt][2] *= sf[2]; Of[sub][nt][3] *= sf[3];
      }
    }

    // O += P V (split-2 x split-2, small->large); V frags shared across subtiles
    __builtin_amdgcn_s_setprio(1);
    #pragma unroll
    for (int kk = 0; kk < 2; ++kk) {
      const int ip = (kk ? iK1 : iK0);
      bf16x8 paf[NSUB], pbf[NSUB];
      #pragma unroll
      for (int sub = 0; sub < NSUB; ++sub) {
        paf[sub] = *(const bf16x8*)((const char*)&Pa[w][sub][0] + ip);
        pbf[sub] = *(const bf16x8*)((const char*)&Pb[w][sub][0] + ip);
      }
      #pragma unroll
      for (int nt = 0; nt < 4; ++nt) {
        const int ib = ip + nt * 2048;
        const bf16x8 vaf = *(const bf16x8*)((const char*)Va + ib);
        const bf16x8 vbf = *(const bf16x8*)((const char*)Vb + ib);
        #pragma unroll
        for (int sub = 0; sub < NSUB; ++sub) {
          f32x4 o = Of[sub][nt];
          o = __builtin_amdgcn_mfma_f32_16x16x32_bf16(pbf[sub], vbf, o, 0, 0, 0);
          o = __builtin_amdgcn_mfma_f32_16x16x32_bf16(pbf[sub], vaf, o, 0, 0, 0);
          o = __builtin_amdgcn_mfma_f32_16x16x32_bf16(paf[sub], vbf, o, 0, 0, 0);
          o = __builtin_amdgcn_mfma_f32_16x16x32_bf16(paf[sub], vaf, o, 0, 0, 0);
          Of[sub][nt] = o;
        }
      }
    }
    __builtin_amdgcn_s_setprio(0);
  }

  // epilogue: normalize, +bias, leaky, store
  #pragma unroll
  for (int sub = 0; sub < NSUB; ++sub) {
    const float inv = 1.0f / lrow[sub];
    float bi[4];
    #pragma unroll
    for (int i = 0; i < 4; ++i) bi[i] = __shfl(inv, 4 * g + i);
    #pragma unroll
    for (int nt = 0; nt < 4; ++nt) {
      #pragma unroll
      for (int i = 0; i < 4; ++i) {
        const int d = nt * 16 + c;
        const int q = qw + sub * 16 + 4 * g + i;
        float o;
        if (LAYER == 1) o = Of[sub][nt][i] * bi[i] + bias[(pass & 3) * 64 + d];
        else            o = Of[sub][nt][i] * bi[i] + bias[d];
        o = (o >= 0.f) ? o : 0.2f * o;
        if (LAYER == 1) {
          const int b = pass >> 2;
          outp[((size_t)b * 4096 + q) * 256 + (pass & 3) * 64 + d] = o;
        } else {
          outp[((size_t)pass * 4096 + q) * 64 + d] = o;
        }
      }
    }
  }
}

extern "C" void kernel_launch(void* const* d_in, const int* in_sizes, int n_in,
                              void* d_out, int out_size, void* d_ws, size_t ws_size,
                              hipStream_t stream) {
  const float* x     = (const float*)d_in[0];
  const float* graph = (const float*)d_in[1];
  const float* Ws    = (const float*)d_in[2];
  const float* bs    = (const float*)d_in[3];
  const float* W_out = (const float*)d_in[4];
  const float* b_out = (const float*)d_in[5];
  char* ws = (char*)d_ws;
  const size_t MiB = 1048576;

  u64* bits   = (u64*)(ws + 0 * MiB);      // 2 MiB
  u16* h1a    = (u16*)(ws + 2 * MiB);      // 8 MiB  [16][4096][64]
  u16* h1b    = (u16*)(ws + 10 * MiB);     // 8 MiB
  u16* h1c    = (u16*)(ws + 18 * MiB);     // 8 MiB
  u16* h1aT   = (u16*)(ws + 26 * MiB);     // 8 MiB  [16][64][4096]
  u16* h1bT   = (u16*)(ws + 34 * MiB);     // 8 MiB
  float* catb = (float*)(ws + 42 * MiB);   // 16 MiB [4][4096][256]
  u16* h2a    = (u16*)(ws + 58 * MiB);     // 2 MiB  [4][4096][64]
  u16* h2b    = (u16*)(ws + 60 * MiB);     // 2 MiB
  u16* h2c    = (u16*)(ws + 62 * MiB);     // 2 MiB
  u16* h2aT   = (u16*)(ws + 64 * MiB);     // 2 MiB
  u16* h2bT   = (u16*)(ws + 66 * MiB);     // 2 MiB  (total 68 MiB)

  pack_kernel<<<4096, 256, 0, stream>>>(graph, bits);
  h1_kernel<<<16384, 256, 0, stream>>>(x, Ws, h1a, h1b, h1c);
  transpose_kernel<<<dim3(64, 16), 256, 0, stream>>>(h1a, h1aT);
  transpose_kernel<<<dim3(64, 16), 256, 0, stream>>>(h1b, h1bT);
  attn_kernel<1, 2><<<dim3(32, 16), 256, 0, stream>>>(h1a, h1b, h1c, h1aT, h1bT, bits, bs, catb);
  h2_kernel<<<4096, 256, 0, stream>>>(catb, W_out, h2a, h2b, h2c);
  transpose_kernel<<<dim3(64, 4), 256, 0, stream>>>(h2a, h2aT);
  transpose_kernel<<<dim3(64, 4), 256, 0, stream>>>(h2b, h2bT);
  attn_kernel<2, 1><<<dim3(64, 4), 256, 0, stream>>>(h2a, h2b, h2c, h2aT, h2bT, bits, b_out, (float*)d_out);
}